// Round 7
// baseline (234.952 us; speedup 1.0000x reference)
//
#include <hip/hip_runtime.h>
#include <cstddef>

#define L_SEQ 32768
#define H_FEAT 512
#define P_STATE 256
#define N2 512              // 2*P (re/im interleaved)
#define CS 32               // scan chunk size
#define NCH (L_SEQ / CS)    // 1024 chunks

typedef __bf16 bf16x8 __attribute__((ext_vector_type(8)));
typedef float f32x4 __attribute__((ext_vector_type(4)));

// async global->LDS, 16B per lane; LDS dst must be uniform base + lane*16
#define GLDS16(g, l) __builtin_amdgcn_global_load_lds( \
    (const __attribute__((address_space(1))) void*)(g), \
    (__attribute__((address_space(3))) void*)(l), 16, 0, 0)

__device__ __forceinline__ unsigned bf_rne(float x) {   // bf16 bits (RNE) in low 16
    unsigned u = __float_as_uint(x);
    return (u + 0x7fffu + ((u >> 16) & 1u)) >> 16;
}
__device__ __forceinline__ float bf_f(unsigned bits) {
    return __uint_as_float(bits << 16);
}
__device__ __forceinline__ float2 cmul(float2 a, float2 b) {
    return make_float2(fmaf(a.x, b.x, -a.y * b.y), fmaf(a.x, b.y, a.y * b.x));
}
// a*b + c
__device__ __forceinline__ float2 cfma(float2 a, float2 b, float2 c) {
    return make_float2(fmaf(a.x, b.x, fmaf(-a.y, b.y, c.x)),
                       fmaf(a.x, b.y, fmaf(a.y, b.x, c.y)));
}

// ---------------------------------------------------------------------------
// Params: W split (bf16 hi/lo, [N2][H]), C2 split ([H][N2]), Abar.
// ---------------------------------------------------------------------------
__global__ __launch_bounds__(256) void param_kernel(
    const float* __restrict__ lr, const float* __restrict__ li,
    const float* __restrict__ b,  const float* __restrict__ c,
    const float* __restrict__ delta,
    ushort* __restrict__ W_hi, ushort* __restrict__ W_lo,
    ushort* __restrict__ C2_hi, ushort* __restrict__ C2_lo,
    float2* __restrict__ Abar)
{
    int tid = blockIdx.x * blockDim.x + threadIdx.x;   // 0 .. P*H-1 (131072)

    {
        int p = tid >> 9;
        int h = tid & 511;
        float step = expf(delta[p]);
        float zr = 0.5f * step * lr[p];
        float zi = 0.5f * step * li[p];
        float dr = 1.0f - zr, di = -zi;
        float den = dr * dr + di * di;
        float blr = dr / den, bli = -di / den;       // BL = 1/(1-z)
        float bbr = blr * step, bbi = bli * step;    // BL*step
        float b0 = b[((size_t)(p * H_FEAT + h)) * 2 + 0];
        float b1 = b[((size_t)(p * H_FEAT + h)) * 2 + 1];
        float vr = bbr * b0 - bbi * b1;              // Re(B_bar)
        float vi = bbr * b1 + bbi * b0;              // Im(B_bar)
        unsigned hr = bf_rne(vr), hl = bf_rne(vr - bf_f(hr));
        unsigned ir = bf_rne(vi), il = bf_rne(vi - bf_f(ir));
        size_t o0 = (size_t)(2 * p) * H_FEAT + h;
        size_t o1 = (size_t)(2 * p + 1) * H_FEAT + h;
        W_hi[o0] = (ushort)hr; W_lo[o0] = (ushort)hl;
        W_hi[o1] = (ushort)ir; W_lo[o1] = (ushort)il;
    }

    {
        int h2 = tid >> 8;
        int p2 = tid & 255;
        float c0 =  2.0f * c[((size_t)(h2 * P_STATE + p2)) * 2 + 0];
        float c1 = -2.0f * c[((size_t)(h2 * P_STATE + p2)) * 2 + 1];
        unsigned h0 = bf_rne(c0), l0 = bf_rne(c0 - bf_f(h0));
        unsigned h1 = bf_rne(c1), l1 = bf_rne(c1 - bf_f(h1));
        size_t o0 = (size_t)h2 * N2 + 2 * p2;
        C2_hi[o0] = (ushort)h0;     C2_lo[o0] = (ushort)l0;
        C2_hi[o0 + 1] = (ushort)h1; C2_lo[o0 + 1] = (ushort)l1;
    }

    if (tid < P_STATE) {
        int p = tid;
        float step = expf(delta[p]);
        float zr = 0.5f * step * lr[p];
        float zi = 0.5f * step * li[p];
        float dr = 1.0f - zr, di = -zi;
        float den = dr * dr + di * di;
        float blr = dr / den, bli = -di / den;
        float nr = 1.0f + zr, ni = zi;
        Abar[p] = make_float2(blr * nr - bli * ni, blr * ni + bli * nr);
    }
}

// ---------------------------------------------------------------------------
// GEMM1 + fused scan-pass1.
// Core: round-0 proven structure. BM=128, BN=256, BK=32, 256 thr (4 waves),
// wave tile 64x128 (4x8 frags), 3 MFMA per frag.  grid = (2, 256).
// Epilogue: 2 phases (64-row Cs restage, full 64 KiB LDS union); 256 threads
// scan 2 chunks in parallel per phase; write `ends`.
// ---------------------------------------------------------------------------
__global__ __launch_bounds__(256, 2) void gemm1(
    const float* __restrict__ A,
    const ushort* __restrict__ Bhi, const ushort* __restrict__ Blo,
    float* __restrict__ C,
    const float2* __restrict__ Abar, float2* __restrict__ ends)
{
    __shared__ ushort sh[32768];            // 64 KiB, carved:
    ushort* As_hi = sh;                     //  8 KiB [128][32]
    ushort* As_lo = sh + 4096;              //  8 KiB
    ushort* Bs_hi = sh + 8192;              // 16 KiB [256][32]
    ushort* Bs_lo = sh + 16384;             // 16 KiB
    float*  Cs    = (float*)sh;             // 64 KiB [64][256] (epilogue reuse)

    const int tid = threadIdx.x;
    const int ln = tid & 63, wv = tid >> 6;
    const int bm = blockIdx.y * 128, bn = blockIdx.x * 256;
    const int m = ln & 15, q = ln >> 4;
    const int wr = (wv >> 1) * 64, wc = (wv & 1) * 128;

    f32x4 acc[4][8] = {};

    for (int k0 = 0; k0 < 512; k0 += 32) {
        // --- B tiles (bf16 hi/lo): 32 wave-chunks of 16 rows, async ---
#pragma unroll
        for (int s = 0; s < 8; s++) {
            int t = wv * 8 + s;            // 0..31
            int ch = t & 15;
            int row = ch * 16 + (ln >> 2);
            const ushort* src = (t < 16 ? Bhi : Blo)
                                + (size_t)(bn + row) * 512 + k0 + (ln & 3) * 8;
            ushort* dst = (t < 16 ? Bs_hi : Bs_lo) + ch * 512 + ln * 8;
            GLDS16(src, dst);
        }
        // --- A tile: f32 load + split to hi/lo bf16 ---
#pragma unroll
        for (int r = 0; r < 4; r++) {
            int idx = tid + r * 256;       // 0..1023
            int row = idx >> 3;
            int c4 = (idx & 7) << 2;
            const float4 v = *(const float4*)(A + (size_t)(bm + row) * 512 + k0 + c4);
            unsigned u0 = __float_as_uint(v.x), u1 = __float_as_uint(v.y);
            unsigned u2 = __float_as_uint(v.z), u3 = __float_as_uint(v.w);
            unsigned hi01 = (u0 >> 16) | (u1 & 0xffff0000u);
            unsigned hi23 = (u2 >> 16) | (u3 & 0xffff0000u);
            float d0 = v.x - __uint_as_float(u0 & 0xffff0000u);
            float d1 = v.y - __uint_as_float(u1 & 0xffff0000u);
            float d2 = v.z - __uint_as_float(u2 & 0xffff0000u);
            float d3 = v.w - __uint_as_float(u3 & 0xffff0000u);
            unsigned lo01 = (__float_as_uint(d0) >> 16) | (__float_as_uint(d1) & 0xffff0000u);
            unsigned lo23 = (__float_as_uint(d2) >> 16) | (__float_as_uint(d3) & 0xffff0000u);
            *(uint2*)(As_hi + row * 32 + c4) = make_uint2(hi01, hi23);
            *(uint2*)(As_lo + row * 32 + c4) = make_uint2(lo01, lo23);
        }
        __syncthreads();

        bf16x8 ah[4], al[4];
#pragma unroll
        for (int i = 0; i < 4; i++) {
            ah[i] = *(const bf16x8*)(As_hi + (wr + i * 16 + m) * 32 + q * 8);
            al[i] = *(const bf16x8*)(As_lo + (wr + i * 16 + m) * 32 + q * 8);
        }
#pragma unroll
        for (int j = 0; j < 8; j++) {
            bf16x8 bh = *(const bf16x8*)(Bs_hi + (wc + j * 16 + m) * 32 + q * 8);
            bf16x8 bl = *(const bf16x8*)(Bs_lo + (wc + j * 16 + m) * 32 + q * 8);
#pragma unroll
            for (int i = 0; i < 4; i++)
                acc[i][j] = __builtin_amdgcn_mfma_f32_16x16x32_bf16(ah[i], bh, acc[i][j], 0, 0, 0);
#pragma unroll
            for (int i = 0; i < 4; i++)
                acc[i][j] = __builtin_amdgcn_mfma_f32_16x16x32_bf16(al[i], bh, acc[i][j], 0, 0, 0);
#pragma unroll
            for (int i = 0; i < 4; i++)
                acc[i][j] = __builtin_amdgcn_mfma_f32_16x16x32_bf16(ah[i], bl, acc[i][j], 0, 0, 0);
        }
        __syncthreads();
    }

    // --- C (Bu) write, f32 ---
#pragma unroll
    for (int i = 0; i < 4; i++)
#pragma unroll
        for (int j = 0; j < 8; j++)
#pragma unroll
            for (int r = 0; r < 4; r++) {
                int row = bm + wr + i * 16 + q * 4 + r;
                int col = bn + wc + j * 16 + m;
                C[(size_t)row * 512 + col] = acc[i][j][r];
            }

    // --- fused pass1: 2 phases, 64-row restage, 256-thread parallel scan ---
    const int p_l = tid & 127;            // complex p within block
    const int lc  = tid >> 7;             // chunk within phase (0/1)
    const float2 Aop = Abar[(bn >> 1) + p_l];
#pragma unroll
    for (int h = 0; h < 2; h++) {
        if ((wv >> 1) == h) {             // waves owning rows h*64..h*64+63
#pragma unroll
            for (int i = 0; i < 4; i++)
#pragma unroll
                for (int j = 0; j < 8; j++)
#pragma unroll
                    for (int r = 0; r < 4; r++)
                        Cs[(i * 16 + q * 4 + r) * 256 + wc + j * 16 + m] = acc[i][j][r];
        }
        __syncthreads();
        {
            float2 s = make_float2(0.f, 0.f);
#pragma unroll 8
            for (int i2 = 0; i2 < 32; i2++) {
                float2 u = *(const float2*)(Cs + (lc * 32 + i2) * 256 + 2 * p_l);
                s = cfma(Aop, s, u);
            }
            ends[(size_t)((bn >> 1) + p_l) * NCH + (bm >> 5) + h * 2 + lc] = s;
        }
        __syncthreads();
    }
}

// ---------------------------------------------------------------------------
// GEMM2 + fused scan-pass3 (parallel segmented scan, rescan form).
// Per K-step: GLDS-stage B (bf16 hi/lo) AND f32 Bu tile (all async, one
// drain); 256 threads (16 p x 4 seg x 4 chunks) scan 8 elements each:
// local zero-init scan keeping inputs in regs, segment-end exchange via
// __shfl, entering-state fold with A^8, then RESCAN s = cfma(A, s, uv[k])
// (no power chain) with bf16 hi/lo pack straight into As.
// out = xs @ C2^T + d*u.  LDS 64 KiB -> 2 blocks/CU.
// ---------------------------------------------------------------------------
__global__ __launch_bounds__(256, 2) void gemm2(
    const float* __restrict__ Bu,
    const ushort* __restrict__ Bhi, const ushort* __restrict__ Blo,
    float* __restrict__ Cout, const float* __restrict__ U,
    const float* __restrict__ dvec,
    const float2* __restrict__ Abar, const float2* __restrict__ carries)
{
    __shared__ ushort As_hi[128 * 32], As_lo[128 * 32];   // 8+8 KiB
    __shared__ ushort Bs_hi[256 * 32], Bs_lo[256 * 32];   // 16+16 KiB
    __shared__ float  Af32[128 * 32];                     // 16 KiB f32 Bu tile
    const int tid = threadIdx.x;
    const int ln = tid & 63, wv = tid >> 6;
    const int bm = blockIdx.y * 128, bn = blockIdx.x * 256;
    const int m = ln & 15, q = ln >> 4;
    const int wr = (wv >> 1) * 64, wc = (wv & 1) * 128;

    // scan role: 16 p-lanes x 4 segments x 4 chunks
    const int pl = tid & 15, sg = (tid >> 4) & 3, chk = tid >> 6;

    f32x4 acc[4][8] = {};

    for (int k0 = 0; k0 < 512; k0 += 32) {
        // --- B tiles (bf16 hi/lo), async ---
#pragma unroll
        for (int s = 0; s < 8; s++) {
            int t = wv * 8 + s;
            int ch = t & 15;
            int row = ch * 16 + (ln >> 2);
            const ushort* src = (t < 16 ? Bhi : Blo)
                                + (size_t)(bn + row) * 512 + k0 + (ln & 3) * 8;
            ushort* dst = (t < 16 ? Bs_hi : Bs_lo) + ch * 512 + ln * 8;
            GLDS16(src, dst);
        }
        // --- f32 Bu tile -> LDS, async (linear layout: GLDS-eligible) ---
#pragma unroll
        for (int r = 0; r < 4; r++) {
            int idx = tid + r * 256;       // 0..1023
            int row = idx >> 3;
            int c4 = (idx & 7) << 2;
            GLDS16(Bu + (size_t)(bm + row) * 512 + k0 + c4, Af32 + row * 32 + c4);
        }
        __syncthreads();

        // --- fused pass3, parallel: every thread owns 8 elements ---
        {
            const int pg = (k0 >> 1) + pl;
            const float2 Aop2 = Abar[pg];
            const float2 A2 = cmul(Aop2, Aop2);
            const float2 A4 = cmul(A2, A2);
            const float2 A8 = cmul(A4, A4);
            const int rbase = chk * 32 + sg * 8;

            // local zero-init scan (chain length 8), inputs kept in regs
            float2 uv[8];
            float2 s = make_float2(0.f, 0.f);
#pragma unroll
            for (int k = 0; k < 8; k++) {
                uv[k] = *(const float2*)(Af32 + (rbase + k) * 32 + 2 * pl);
                s = cfma(Aop2, s, uv[k]);
            }
            // segment ends of sg 0..2 via intra-wave shuffles
            const float2 e0 = make_float2(__shfl(s.x, pl),      __shfl(s.y, pl));
            const float2 e1 = make_float2(__shfl(s.x, pl + 16), __shfl(s.y, pl + 16));
            const float2 e2 = make_float2(__shfl(s.x, pl + 32), __shfl(s.y, pl + 32));
            // entering state for this segment
            float2 S = carries[(size_t)pg * NCH + (bm >> 5) + chk];
            if (sg >= 1) S = cfma(A8, S, e0);
            if (sg >= 2) S = cfma(A8, S, e1);
            if (sg >= 3) S = cfma(A8, S, e2);
            // rescan with correct init + bf16 hi/lo pack into As
#pragma unroll
            for (int k = 0; k < 8; k++) {
                S = cfma(Aop2, S, uv[k]);
                unsigned hr  = bf_rne(S.x);
                unsigned lr2 = __float_as_uint(S.x - bf_f(hr)) >> 16;
                unsigned hi_ = bf_rne(S.y);
                unsigned li2 = __float_as_uint(S.y - bf_f(hi_)) >> 16;
                const int row = rbase + k;
                *(unsigned*)(As_hi + row * 32 + 2 * pl) = hr | (hi_ << 16);
                *(unsigned*)(As_lo + row * 32 + 2 * pl) = lr2 | (li2 << 16);
            }
        }
        __syncthreads();

        bf16x8 ah[4], al[4];
#pragma unroll
        for (int i = 0; i < 4; i++) {
            ah[i] = *(const bf16x8*)(As_hi + (wr + i * 16 + m) * 32 + q * 8);
            al[i] = *(const bf16x8*)(As_lo + (wr + i * 16 + m) * 32 + q * 8);
        }
#pragma unroll
        for (int j = 0; j < 8; j++) {
            bf16x8 bh = *(const bf16x8*)(Bs_hi + (wc + j * 16 + m) * 32 + q * 8);
            bf16x8 bl = *(const bf16x8*)(Bs_lo + (wc + j * 16 + m) * 32 + q * 8);
#pragma unroll
            for (int i = 0; i < 4; i++)
                acc[i][j] = __builtin_amdgcn_mfma_f32_16x16x32_bf16(ah[i], bh, acc[i][j], 0, 0, 0);
#pragma unroll
            for (int i = 0; i < 4; i++)
                acc[i][j] = __builtin_amdgcn_mfma_f32_16x16x32_bf16(al[i], bh, acc[i][j], 0, 0, 0);
#pragma unroll
            for (int i = 0; i < 4; i++)
                acc[i][j] = __builtin_amdgcn_mfma_f32_16x16x32_bf16(ah[i], bl, acc[i][j], 0, 0, 0);
        }
        __syncthreads();
    }

#pragma unroll
    for (int i = 0; i < 4; i++)
#pragma unroll
        for (int j = 0; j < 8; j++) {
            int col = bn + wc + j * 16 + m;
            float dv = dvec[col];
#pragma unroll
            for (int r = 0; r < 4; r++) {
                int row = bm + wr + i * 16 + q * 4 + r;
                Cout[(size_t)row * 512 + col] =
                    acc[i][j][r] + dv * U[(size_t)row * 512 + col];
            }
        }
}

// ---------------------------------------------------------------------------
// Scan pass 2: per-p Kogge-Stone over NCH chunk pairs (A^CS, end) -> carries.
// ---------------------------------------------------------------------------
__global__ __launch_bounds__(1024) void scan_pass2(
    const float2* __restrict__ ends, const float2* __restrict__ Abar,
    float2* __restrict__ carries)
{
    __shared__ float2 sA[NCH];
    __shared__ float2 sB[NCH];
    int p = blockIdx.x;
    int t = threadIdx.x;

    float2 a = Abar[p];
#pragma unroll
    for (int i = 0; i < 5; i++) {    // a^32
        float nr = a.x * a.x - a.y * a.y;
        float ni = 2.f * a.x * a.y;
        a = make_float2(nr, ni);
    }
    float2 A = a;
    float2 bv = ends[(size_t)p * NCH + t];
    sA[t] = A; sB[t] = bv;
    __syncthreads();

    for (int off = 1; off < NCH; off <<= 1) {
        float2 pa, pb;
        bool act = (t >= off);
        if (act) { pa = sA[t - off]; pb = sB[t - off]; }
        __syncthreads();
        if (act) {
            float2 nA = make_float2(A.x * pa.x - A.y * pa.y,
                                    A.x * pa.y + A.y * pa.x);
            float2 nB = make_float2(fmaf(A.x, pb.x, fmaf(-A.y, pb.y, bv.x)),
                                    fmaf(A.x, pb.y, fmaf(A.y, pb.x, bv.y)));
            A = nA; bv = nB;
            sA[t] = A; sB[t] = bv;
        }
        __syncthreads();
    }

    float2 carry = (t == 0) ? make_float2(0.f, 0.f) : sB[t - 1];
    carries[(size_t)p * NCH + t] = carry;
}

// ---------------------------------------------------------------------------
extern "C" void kernel_launch(void* const* d_in, const int* in_sizes, int n_in,
                              void* d_out, int out_size, void* d_ws, size_t ws_size,
                              hipStream_t stream) {
    const float* u     = (const float*)d_in[0];   // [L][H]
    const float* lr    = (const float*)d_in[1];   // [P]
    const float* li    = (const float*)d_in[2];   // [P]
    const float* b     = (const float*)d_in[3];   // [P][H][2]
    const float* c     = (const float*)d_in[4];   // [H][P][2]
    const float* dvec  = (const float*)d_in[5];   // [H]
    const float* delta = (const float*)d_in[6];   // [P]
    float* out = (float*)d_out;

    // workspace layout
    char* p = (char*)d_ws;
    float*  Bu      = (float*)p;   p += (size_t)L_SEQ * N2 * 4;        // 64 MiB
    float2* ends    = (float2*)p;  p += (size_t)P_STATE * NCH * 8;     // 2 MiB
    float2* carries = (float2*)p;  p += (size_t)P_STATE * NCH * 8;     // 2 MiB
    ushort* W_hi    = (ushort*)p;  p += (size_t)N2 * H_FEAT * 2;
    ushort* W_lo    = (ushort*)p;  p += (size_t)N2 * H_FEAT * 2;
    ushort* C2_hi   = (ushort*)p;  p += (size_t)H_FEAT * N2 * 2;
    ushort* C2_lo   = (ushort*)p;  p += (size_t)H_FEAT * N2 * 2;
    float2* Abar    = (float2*)p;  p += (size_t)P_STATE * 8;

    // 1. params (+ weight splitting)
    param_kernel<<<(P_STATE * H_FEAT) / 256, 256, 0, stream>>>(
        lr, li, b, c, delta, W_hi, W_lo, C2_hi, C2_lo, Abar);

    // 2. GEMM1: Bu = u @ W^T  (+ fused pass1 -> ends)
    {
        dim3 grid(N2 / 256, L_SEQ / 128);
        gemm1<<<grid, 256, 0, stream>>>(u, W_hi, W_lo, Bu, Abar, ends);
    }

    // 3. chunk-carry propagation
    scan_pass2<<<P_STATE, NCH, 0, stream>>>(ends, Abar, carries);

    // 4. GEMM2 (+ fused parallel pass3): out = scan(Bu) @ C2^T + d*u
    {
        dim3 grid(H_FEAT / 256, L_SEQ / 128);
        gemm2<<<grid, 256, 0, stream>>>(Bu, C2_hi, C2_lo, out, u, dvec,
                                        Abar, carries);
    }
}

// Round 8
// 231.241 us; speedup vs baseline: 1.0160x; 1.0160x over previous
//
#include <hip/hip_runtime.h>
#include <cstddef>

#define L_SEQ 32768
#define H_FEAT 512
#define P_STATE 256
#define N2 512              // 2*P (re/im interleaved)
#define CS 32               // scan chunk size
#define NCH (L_SEQ / CS)    // 1024 chunks

typedef __bf16 bf16x8 __attribute__((ext_vector_type(8)));
typedef float f32x4 __attribute__((ext_vector_type(4)));

// async global->LDS, 16B per lane; LDS dst must be uniform base + lane*16
#define GLDS16(g, l) __builtin_amdgcn_global_load_lds( \
    (const __attribute__((address_space(1))) void*)(g), \
    (__attribute__((address_space(3))) void*)(l), 16, 0, 0)

#define SCHED_FENCE() __builtin_amdgcn_sched_barrier(0)

__device__ __forceinline__ unsigned bf_rne(float x) {   // bf16 bits (RNE) in low 16
    unsigned u = __float_as_uint(x);
    return (u + 0x7fffu + ((u >> 16) & 1u)) >> 16;
}
__device__ __forceinline__ float bf_f(unsigned bits) {
    return __uint_as_float(bits << 16);
}
__device__ __forceinline__ float2 cmul(float2 a, float2 b) {
    return make_float2(fmaf(a.x, b.x, -a.y * b.y), fmaf(a.x, b.y, a.y * b.x));
}
// a*b + c
__device__ __forceinline__ float2 cfma(float2 a, float2 b, float2 c) {
    return make_float2(fmaf(a.x, b.x, fmaf(-a.y, b.y, c.x)),
                       fmaf(a.x, b.y, fmaf(a.y, b.x, c.y)));
}

// ---------------------------------------------------------------------------
// Params: W split (bf16 hi/lo, [N2][H]), C2 split ([H][N2]), Abar.
// ---------------------------------------------------------------------------
__global__ __launch_bounds__(256) void param_kernel(
    const float* __restrict__ lr, const float* __restrict__ li,
    const float* __restrict__ b,  const float* __restrict__ c,
    const float* __restrict__ delta,
    ushort* __restrict__ W_hi, ushort* __restrict__ W_lo,
    ushort* __restrict__ C2_hi, ushort* __restrict__ C2_lo,
    float2* __restrict__ Abar)
{
    int tid = blockIdx.x * blockDim.x + threadIdx.x;   // 0 .. P*H-1 (131072)

    {
        int p = tid >> 9;
        int h = tid & 511;
        float step = expf(delta[p]);
        float zr = 0.5f * step * lr[p];
        float zi = 0.5f * step * li[p];
        float dr = 1.0f - zr, di = -zi;
        float den = dr * dr + di * di;
        float blr = dr / den, bli = -di / den;       // BL = 1/(1-z)
        float bbr = blr * step, bbi = bli * step;    // BL*step
        float b0 = b[((size_t)(p * H_FEAT + h)) * 2 + 0];
        float b1 = b[((size_t)(p * H_FEAT + h)) * 2 + 1];
        float vr = bbr * b0 - bbi * b1;              // Re(B_bar)
        float vi = bbr * b1 + bbi * b0;              // Im(B_bar)
        unsigned hr = bf_rne(vr), hl = bf_rne(vr - bf_f(hr));
        unsigned ir = bf_rne(vi), il = bf_rne(vi - bf_f(ir));
        size_t o0 = (size_t)(2 * p) * H_FEAT + h;
        size_t o1 = (size_t)(2 * p + 1) * H_FEAT + h;
        W_hi[o0] = (ushort)hr; W_lo[o0] = (ushort)hl;
        W_hi[o1] = (ushort)ir; W_lo[o1] = (ushort)il;
    }

    {
        int h2 = tid >> 8;
        int p2 = tid & 255;
        float c0 =  2.0f * c[((size_t)(h2 * P_STATE + p2)) * 2 + 0];
        float c1 = -2.0f * c[((size_t)(h2 * P_STATE + p2)) * 2 + 1];
        unsigned h0 = bf_rne(c0), l0 = bf_rne(c0 - bf_f(h0));
        unsigned h1 = bf_rne(c1), l1 = bf_rne(c1 - bf_f(h1));
        size_t o0 = (size_t)h2 * N2 + 2 * p2;
        C2_hi[o0] = (ushort)h0;     C2_lo[o0] = (ushort)l0;
        C2_hi[o0 + 1] = (ushort)h1; C2_lo[o0 + 1] = (ushort)l1;
    }

    if (tid < P_STATE) {
        int p = tid;
        float step = expf(delta[p]);
        float zr = 0.5f * step * lr[p];
        float zi = 0.5f * step * li[p];
        float dr = 1.0f - zr, di = -zi;
        float den = dr * dr + di * di;
        float blr = dr / den, bli = -di / den;
        float nr = 1.0f + zr, ni = zi;
        Abar[p] = make_float2(blr * nr - bli * ni, blr * ni + bli * nr);
    }
}

// ---------------------------------------------------------------------------
// GEMM1 + fused scan-pass1.  (unchanged from round 7)
// Core: round-0 proven structure. BM=128, BN=256, BK=32, 256 thr (4 waves),
// wave tile 64x128 (4x8 frags), 3 MFMA per frag.  grid = (2, 256).
// Epilogue: 2 phases (64-row Cs restage, full 64 KiB LDS union); 256 threads
// scan 2 chunks in parallel per phase; write `ends`.
// ---------------------------------------------------------------------------
__global__ __launch_bounds__(256, 2) void gemm1(
    const float* __restrict__ A,
    const ushort* __restrict__ Bhi, const ushort* __restrict__ Blo,
    float* __restrict__ C,
    const float2* __restrict__ Abar, float2* __restrict__ ends)
{
    __shared__ ushort sh[32768];            // 64 KiB, carved:
    ushort* As_hi = sh;                     //  8 KiB [128][32]
    ushort* As_lo = sh + 4096;              //  8 KiB
    ushort* Bs_hi = sh + 8192;              // 16 KiB [256][32]
    ushort* Bs_lo = sh + 16384;             // 16 KiB
    float*  Cs    = (float*)sh;             // 64 KiB [64][256] (epilogue reuse)

    const int tid = threadIdx.x;
    const int ln = tid & 63, wv = tid >> 6;
    const int bm = blockIdx.y * 128, bn = blockIdx.x * 256;
    const int m = ln & 15, q = ln >> 4;
    const int wr = (wv >> 1) * 64, wc = (wv & 1) * 128;

    f32x4 acc[4][8] = {};

    for (int k0 = 0; k0 < 512; k0 += 32) {
        // --- B tiles (bf16 hi/lo): 32 wave-chunks of 16 rows, async ---
#pragma unroll
        for (int s = 0; s < 8; s++) {
            int t = wv * 8 + s;            // 0..31
            int ch = t & 15;
            int row = ch * 16 + (ln >> 2);
            const ushort* src = (t < 16 ? Bhi : Blo)
                                + (size_t)(bn + row) * 512 + k0 + (ln & 3) * 8;
            ushort* dst = (t < 16 ? Bs_hi : Bs_lo) + ch * 512 + ln * 8;
            GLDS16(src, dst);
        }
        // --- A tile: f32 load + split to hi/lo bf16 ---
#pragma unroll
        for (int r = 0; r < 4; r++) {
            int idx = tid + r * 256;       // 0..1023
            int row = idx >> 3;
            int c4 = (idx & 7) << 2;
            const float4 v = *(const float4*)(A + (size_t)(bm + row) * 512 + k0 + c4);
            unsigned u0 = __float_as_uint(v.x), u1 = __float_as_uint(v.y);
            unsigned u2 = __float_as_uint(v.z), u3 = __float_as_uint(v.w);
            unsigned hi01 = (u0 >> 16) | (u1 & 0xffff0000u);
            unsigned hi23 = (u2 >> 16) | (u3 & 0xffff0000u);
            float d0 = v.x - __uint_as_float(u0 & 0xffff0000u);
            float d1 = v.y - __uint_as_float(u1 & 0xffff0000u);
            float d2 = v.z - __uint_as_float(u2 & 0xffff0000u);
            float d3 = v.w - __uint_as_float(u3 & 0xffff0000u);
            unsigned lo01 = (__float_as_uint(d0) >> 16) | (__float_as_uint(d1) & 0xffff0000u);
            unsigned lo23 = (__float_as_uint(d2) >> 16) | (__float_as_uint(d3) & 0xffff0000u);
            *(uint2*)(As_hi + row * 32 + c4) = make_uint2(hi01, hi23);
            *(uint2*)(As_lo + row * 32 + c4) = make_uint2(lo01, lo23);
        }
        __syncthreads();

        bf16x8 ah[4], al[4];
#pragma unroll
        for (int i = 0; i < 4; i++) {
            ah[i] = *(const bf16x8*)(As_hi + (wr + i * 16 + m) * 32 + q * 8);
            al[i] = *(const bf16x8*)(As_lo + (wr + i * 16 + m) * 32 + q * 8);
        }
#pragma unroll
        for (int j = 0; j < 8; j++) {
            bf16x8 bh = *(const bf16x8*)(Bs_hi + (wc + j * 16 + m) * 32 + q * 8);
            bf16x8 bl = *(const bf16x8*)(Bs_lo + (wc + j * 16 + m) * 32 + q * 8);
#pragma unroll
            for (int i = 0; i < 4; i++)
                acc[i][j] = __builtin_amdgcn_mfma_f32_16x16x32_bf16(ah[i], bh, acc[i][j], 0, 0, 0);
#pragma unroll
            for (int i = 0; i < 4; i++)
                acc[i][j] = __builtin_amdgcn_mfma_f32_16x16x32_bf16(al[i], bh, acc[i][j], 0, 0, 0);
#pragma unroll
            for (int i = 0; i < 4; i++)
                acc[i][j] = __builtin_amdgcn_mfma_f32_16x16x32_bf16(ah[i], bl, acc[i][j], 0, 0, 0);
        }
        __syncthreads();
    }

    // --- C (Bu) write, f32 ---
#pragma unroll
    for (int i = 0; i < 4; i++)
#pragma unroll
        for (int j = 0; j < 8; j++)
#pragma unroll
            for (int r = 0; r < 4; r++) {
                int row = bm + wr + i * 16 + q * 4 + r;
                int col = bn + wc + j * 16 + m;
                C[(size_t)row * 512 + col] = acc[i][j][r];
            }

    // --- fused pass1: 2 phases, 64-row restage, 256-thread parallel scan ---
    const int p_l = tid & 127;            // complex p within block
    const int lc  = tid >> 7;             // chunk within phase (0/1)
    const float2 Aop = Abar[(bn >> 1) + p_l];
#pragma unroll
    for (int h = 0; h < 2; h++) {
        if ((wv >> 1) == h) {             // waves owning rows h*64..h*64+63
#pragma unroll
            for (int i = 0; i < 4; i++)
#pragma unroll
                for (int j = 0; j < 8; j++)
#pragma unroll
                    for (int r = 0; r < 4; r++)
                        Cs[(i * 16 + q * 4 + r) * 256 + wc + j * 16 + m] = acc[i][j][r];
        }
        __syncthreads();
        {
            float2 s = make_float2(0.f, 0.f);
#pragma unroll 8
            for (int i2 = 0; i2 < 32; i2++) {
                float2 u = *(const float2*)(Cs + (lc * 32 + i2) * 256 + 2 * p_l);
                s = cfma(Aop, s, u);
            }
            ends[(size_t)((bn >> 1) + p_l) * NCH + (bm >> 5) + h * 2 + lc] = s;
        }
        __syncthreads();
    }
}

// ---------------------------------------------------------------------------
// GEMM2 + fused scan-pass3 (round-5 scan/staging, NEW split-drain barriers).
// Per K-step, issue order (oldest->youngest vmem): carries+Abar, 4 dense A
// float4 loads, 8 B-GLDS.  ds_write of A auto-waits vmcnt(8) -> B stays in
// flight; s_barrier; scan phase (parallel segmented, power-chain form) runs
// while B flies; vmcnt(0) only after scan; s_barrier; MFMA.
// out = xs @ C2^T + d*u.  LDS 64 KiB -> 2 blocks/CU.
// ---------------------------------------------------------------------------
__global__ __launch_bounds__(256, 2) void gemm2(
    const float* __restrict__ Bu,
    const ushort* __restrict__ Bhi, const ushort* __restrict__ Blo,
    float* __restrict__ Cout, const float* __restrict__ U,
    const float* __restrict__ dvec,
    const float2* __restrict__ Abar, const float2* __restrict__ carries)
{
    __shared__ ushort As_hi[128 * 32], As_lo[128 * 32];   // 8+8 KiB
    __shared__ ushort Bs_hi[256 * 32], Bs_lo[256 * 32];   // 16+16 KiB
    __shared__ float  Af32[128 * 32];                     // 16 KiB f32 Bu tile
    const int tid = threadIdx.x;
    const int ln = tid & 63, wv = tid >> 6;
    const int bm = blockIdx.y * 128, bn = blockIdx.x * 256;
    const int m = ln & 15, q = ln >> 4;
    const int wr = (wv >> 1) * 64, wc = (wv & 1) * 128;

    // scan role: 16 p-lanes x 4 segments x 4 chunks
    const int pl = tid & 15, sg = (tid >> 4) & 3, chk = tid >> 6;

    f32x4 acc[4][8] = {};

    for (int k0 = 0; k0 < 512; k0 += 32) {
        // (1) oldest vmem: scan operands for this K-step
        const int pg = (k0 >> 1) + pl;
        float2 S = carries[(size_t)pg * NCH + (bm >> 5) + chk];
        float2 Aop2 = Abar[pg];
        SCHED_FENCE();
        // (2) dense A tile f32 loads (reg-staged)
        float4 av[4];
#pragma unroll
        for (int r = 0; r < 4; r++) {
            int idx = tid + r * 256;       // 0..1023
            int row = idx >> 3;
            int c4 = (idx & 7) << 2;
            av[r] = *(const float4*)(Bu + (size_t)(bm + row) * 512 + k0 + c4);
        }
        SCHED_FENCE();
        // (3) B tiles via GLDS (youngest) -- stay in flight through the scan
#pragma unroll
        for (int s = 0; s < 8; s++) {
            int t = wv * 8 + s;
            int ch = t & 15;
            int row = ch * 16 + (ln >> 2);
            const ushort* src = (t < 16 ? Bhi : Blo)
                                + (size_t)(bn + row) * 512 + k0 + (ln & 3) * 8;
            ushort* dst = (t < 16 ? Bs_hi : Bs_lo) + ch * 512 + ln * 8;
            GLDS16(src, dst);
        }
        SCHED_FENCE();
        // (4) A -> LDS (auto-wait vmcnt(8): A landed, B still flying)
#pragma unroll
        for (int r = 0; r < 4; r++) {
            int idx = tid + r * 256;
            int row = idx >> 3;
            int c4 = (idx & 7) << 2;
            *(float4*)(Af32 + row * 32 + c4) = av[r];
        }
        asm volatile("s_waitcnt vmcnt(8) lgkmcnt(0)" ::: "memory");
        SCHED_FENCE();
        __builtin_amdgcn_s_barrier();      // Af32 visible; B-GLDS in flight
        SCHED_FENCE();

        // (5) scan phase (round-5 form) -- hides B-GLDS flight
        {
            const float2 A2 = cmul(Aop2, Aop2);
            const float2 A4 = cmul(A2, A2);
            const float2 A8 = cmul(A4, A4);
            const int rbase = chk * 32 + sg * 8;

            // local zero-init scan (chain length 8), keep partials
            float2 lv[8];
            float2 s = make_float2(0.f, 0.f);
#pragma unroll
            for (int k = 0; k < 8; k++) {
                const float2 uvv = *(const float2*)(Af32 + (rbase + k) * 32 + 2 * pl);
                s = cfma(Aop2, s, uvv);
                lv[k] = s;
            }
            // segment ends of sg 0..2 via intra-wave shuffles
            const float2 e0 = make_float2(__shfl(s.x, pl),      __shfl(s.y, pl));
            const float2 e1 = make_float2(__shfl(s.x, pl + 16), __shfl(s.y, pl + 16));
            const float2 e2 = make_float2(__shfl(s.x, pl + 32), __shfl(s.y, pl + 32));
            // entering state for this segment
            if (sg >= 1) S = cfma(A8, S, e0);
            if (sg >= 2) S = cfma(A8, S, e1);
            if (sg >= 3) S = cfma(A8, S, e2);
            // correction + bf16 hi/lo pack into As
            float2 pw = Aop2;
#pragma unroll
            for (int k = 0; k < 8; k++) {
                const float sr = fmaf(pw.x, S.x, fmaf(-pw.y, S.y, lv[k].x));
                const float si = fmaf(pw.x, S.y, fmaf(pw.y, S.x, lv[k].y));
                unsigned hr  = bf_rne(sr);
                unsigned lr2 = __float_as_uint(sr - bf_f(hr)) >> 16;
                unsigned hi_ = bf_rne(si);
                unsigned li2 = __float_as_uint(si - bf_f(hi_)) >> 16;
                const int row = rbase + k;
                *(unsigned*)(As_hi + row * 32 + 2 * pl) = hr | (hi_ << 16);
                *(unsigned*)(As_lo + row * 32 + 2 * pl) = lr2 | (li2 << 16);
                pw = cmul(pw, Aop2);
            }
        }
        asm volatile("s_waitcnt vmcnt(0) lgkmcnt(0)" ::: "memory");
        SCHED_FENCE();
        __builtin_amdgcn_s_barrier();      // Bs landed + As visible
        SCHED_FENCE();

        // (6) MFMA phase
        bf16x8 ah[4], al[4];
#pragma unroll
        for (int i = 0; i < 4; i++) {
            ah[i] = *(const bf16x8*)(As_hi + (wr + i * 16 + m) * 32 + q * 8);
            al[i] = *(const bf16x8*)(As_lo + (wr + i * 16 + m) * 32 + q * 8);
        }
#pragma unroll
        for (int j = 0; j < 8; j++) {
            bf16x8 bh = *(const bf16x8*)(Bs_hi + (wc + j * 16 + m) * 32 + q * 8);
            bf16x8 bl = *(const bf16x8*)(Bs_lo + (wc + j * 16 + m) * 32 + q * 8);
#pragma unroll
            for (int i = 0; i < 4; i++)
                acc[i][j] = __builtin_amdgcn_mfma_f32_16x16x32_bf16(ah[i], bh, acc[i][j], 0, 0, 0);
#pragma unroll
            for (int i = 0; i < 4; i++)
                acc[i][j] = __builtin_amdgcn_mfma_f32_16x16x32_bf16(al[i], bh, acc[i][j], 0, 0, 0);
#pragma unroll
            for (int i = 0; i < 4; i++)
                acc[i][j] = __builtin_amdgcn_mfma_f32_16x16x32_bf16(ah[i], bl, acc[i][j], 0, 0, 0);
        }
        __syncthreads();                   // end-of-iter LDS reuse guard
    }

#pragma unroll
    for (int i = 0; i < 4; i++)
#pragma unroll
        for (int j = 0; j < 8; j++) {
            int col = bn + wc + j * 16 + m;
            float dv = dvec[col];
#pragma unroll
            for (int r = 0; r < 4; r++) {
                int row = bm + wr + i * 16 + q * 4 + r;
                Cout[(size_t)row * 512 + col] =
                    acc[i][j][r] + dv * U[(size_t)row * 512 + col];
            }
        }
}

// ---------------------------------------------------------------------------
// Scan pass 2: per-p Kogge-Stone over NCH chunk pairs (A^CS, end) -> carries.
// ---------------------------------------------------------------------------
__global__ __launch_bounds__(1024) void scan_pass2(
    const float2* __restrict__ ends, const float2* __restrict__ Abar,
    float2* __restrict__ carries)
{
    __shared__ float2 sA[NCH];
    __shared__ float2 sB[NCH];
    int p = blockIdx.x;
    int t = threadIdx.x;

    float2 a = Abar[p];
#pragma unroll
    for (int i = 0; i < 5; i++) {    // a^32
        float nr = a.x * a.x - a.y * a.y;
        float ni = 2.f * a.x * a.y;
        a = make_float2(nr, ni);
    }
    float2 A = a;
    float2 bv = ends[(size_t)p * NCH + t];
    sA[t] = A; sB[t] = bv;
    __syncthreads();

    for (int off = 1; off < NCH; off <<= 1) {
        float2 pa, pb;
        bool act = (t >= off);
        if (act) { pa = sA[t - off]; pb = sB[t - off]; }
        __syncthreads();
        if (act) {
            float2 nA = make_float2(A.x * pa.x - A.y * pa.y,
                                    A.x * pa.y + A.y * pa.x);
            float2 nB = make_float2(fmaf(A.x, pb.x, fmaf(-A.y, pb.y, bv.x)),
                                    fmaf(A.x, pb.y, fmaf(A.y, pb.x, bv.y)));
            A = nA; bv = nB;
            sA[t] = A; sB[t] = bv;
        }
        __syncthreads();
    }

    float2 carry = (t == 0) ? make_float2(0.f, 0.f) : sB[t - 1];
    carries[(size_t)p * NCH + t] = carry;
}

// ---------------------------------------------------------------------------
extern "C" void kernel_launch(void* const* d_in, const int* in_sizes, int n_in,
                              void* d_out, int out_size, void* d_ws, size_t ws_size,
                              hipStream_t stream) {
    const float* u     = (const float*)d_in[0];   // [L][H]
    const float* lr    = (const float*)d_in[1];   // [P]
    const float* li    = (const float*)d_in[2];   // [P]
    const float* b     = (const float*)d_in[3];   // [P][H][2]
    const float* c     = (const float*)d_in[4];   // [H][P][2]
    const float* dvec  = (const float*)d_in[5];   // [H]
    const float* delta = (const float*)d_in[6];   // [P]
    float* out = (float*)d_out;

    // workspace layout
    char* p = (char*)d_ws;
    float*  Bu      = (float*)p;   p += (size_t)L_SEQ * N2 * 4;        // 64 MiB
    float2* ends    = (float2*)p;  p += (size_t)P_STATE * NCH * 8;     // 2 MiB
    float2* carries = (float2*)p;  p += (size_t)P_STATE * NCH * 8;     // 2 MiB
    ushort* W_hi    = (ushort*)p;  p += (size_t)N2 * H_FEAT * 2;
    ushort* W_lo    = (ushort*)p;  p += (size_t)N2 * H_FEAT * 2;
    ushort* C2_hi   = (ushort*)p;  p += (size_t)H_FEAT * N2 * 2;
    ushort* C2_lo   = (ushort*)p;  p += (size_t)H_FEAT * N2 * 2;
    float2* Abar    = (float2*)p;  p += (size_t)P_STATE * 8;

    // 1. params (+ weight splitting)
    param_kernel<<<(P_STATE * H_FEAT) / 256, 256, 0, stream>>>(
        lr, li, b, c, delta, W_hi, W_lo, C2_hi, C2_lo, Abar);

    // 2. GEMM1: Bu = u @ W^T  (+ fused pass1 -> ends)
    {
        dim3 grid(N2 / 256, L_SEQ / 128);
        gemm1<<<grid, 256, 0, stream>>>(u, W_hi, W_lo, Bu, Abar, ends);
    }

    // 3. chunk-carry propagation
    scan_pass2<<<P_STATE, NCH, 0, stream>>>(ends, Abar, carries);

    // 4. GEMM2 (+ fused parallel pass3, split-drain): out = scan(Bu) @ C2^T + d*u
    {
        dim3 grid(H_FEAT / 256, L_SEQ / 128);
        gemm2<<<grid, 256, 0, stream>>>(Bu, C2_hi, C2_lo, out, u, dvec,
                                        Abar, carries);
    }
}